// Round 3
// baseline (3417.475 us; speedup 1.0000x reference)
//
#include <hip/hip_runtime.h>
#include <math.h>

namespace {

constexpr int B = 2, S = 2048, NH = 32, NKV = 8, HD = 64, NG = 4;
constexpr int M = B * S;                      // 4096 rows
constexpr int H = 2048;                       // hidden (= K dim of projections)
constexpr int CHUNK = 64, NCHUNK = S / CHUNK; // 32 chunks
constexpr float GATE_NORM = 16.0f;

// ---- workspace layout (floats), 17,072,128 floats = 68.3 MB.
// Attention / GLA outputs are written IN PLACE over Q (race-free: each Q slice
// [b, tile, h] is read only by block (tile,h,b) at block start and written only
// by that block at block end; slices disjoint across blocks).
constexpr size_t OFS_COS = 0;
constexpr size_t OFS_SIN = OFS_COS + (size_t)S * HD;                    // 131072
constexpr size_t OFS_Q   = OFS_SIN + (size_t)S * HD;                    // q (teacher then student); overwritten by attn/gla out
constexpr size_t OFS_K   = OFS_Q   + (size_t)M * (NH * HD);             // k  [M][512]
constexpr size_t OFS_V   = OFS_K   + (size_t)M * (NKV * HD);            // v  [M][512]
constexpr size_t OFS_AC  = OFS_V   + (size_t)M * (NKV * HD);            // local gate cumsum [b][kv][s][64]
constexpr size_t OFS_AT  = OFS_AC  + (size_t)B * NKV * S * HD;          // per-chunk total  [b][kv][c][64]
constexpr size_t OFS_T   = OFS_AT  + (size_t)B * NKV * NCHUNK * HD;     // T_c then S_init [b][kv][c][64][64]

// ---------------------------------------------------------------- RoPE tables
__global__ void rope_table(float* __restrict__ cs, float* __restrict__ sn) {
  int id = blockIdx.x * blockDim.x + threadIdx.x;  // S * 32
  if (id >= S * (HD / 2)) return;
  int s = id >> 5, i = id & 31;
  double inv = exp(-(double)(2 * i) / 64.0 * log(500000.0));
  float f = (float)s * (float)inv;
  float c = cosf(f), si = sinf(f);
  cs[s * HD + i] = c;  cs[s * HD + i + 32] = c;
  sn[s * HD + i] = si; sn[s * HD + i + 32] = si;
}

// ------------------------------------------------------- fp32 GEMM, C = A*W^T
// A [Mm,Kk] row-major, W [Nn,Kk] row-major, C [Mm,Nn]. Templated tile; k-major
// LDS with +4 pad (conflict-free float4 reads; transpose writes 2-way = free).
// Register prefetch of tile k+1 under compute of tile k.
template <int BM, int BN, int TM, int TN, int NT>
__global__ __launch_bounds__(NT) void gemm_nt(
    const float* __restrict__ A, const float* __restrict__ W,
    float* __restrict__ C, int Mm, int Nn, int Kk) {
  constexpr int BK = 16, PD = 4;
  constexpr int AF4 = BM * BK / 4 / NT;  // float4 loads per thread (A)
  constexpr int WF4 = BN * BK / 4 / NT;  // float4 loads per thread (W)
  static_assert(AF4 >= 1 && WF4 >= 1, "tile too small for thread count");
  __shared__ float As[BK][BM + PD];
  __shared__ float Wsh[BK][BN + PD];
  const int t = threadIdx.x;
  const int bm = blockIdx.x * BM, bn = blockIdx.y * BN;
  const int tx = t % (BN / TN);
  const int ty = t / (BN / TN);

  float4 ar[AF4], wr[WF4];
  auto aload = [&](int k0) {
#pragma unroll
    for (int i = 0; i < AF4; ++i) {
      int f = t + i * NT, r = f >> 2, c = (f & 3) << 2;
      ar[i] = *(const float4*)(A + (size_t)(bm + r) * Kk + k0 + c);
    }
#pragma unroll
    for (int i = 0; i < WF4; ++i) {
      int f = t + i * NT, r = f >> 2, c = (f & 3) << 2;
      wr[i] = *(const float4*)(W + (size_t)(bn + r) * Kk + k0 + c);
    }
  };
  auto sstore = [&]() {
#pragma unroll
    for (int i = 0; i < AF4; ++i) {
      int f = t + i * NT, r = f >> 2, c = (f & 3) << 2;
      As[c + 0][r] = ar[i].x; As[c + 1][r] = ar[i].y;
      As[c + 2][r] = ar[i].z; As[c + 3][r] = ar[i].w;
    }
#pragma unroll
    for (int i = 0; i < WF4; ++i) {
      int f = t + i * NT, r = f >> 2, c = (f & 3) << 2;
      Wsh[c + 0][r] = wr[i].x; Wsh[c + 1][r] = wr[i].y;
      Wsh[c + 2][r] = wr[i].z; Wsh[c + 3][r] = wr[i].w;
    }
  };

  float acc[TM][TN] = {};
  aload(0);
  for (int k0 = 0;;) {
    __syncthreads();  // previous iter's LDS reads complete
    sstore();
    __syncthreads();
    k0 += BK;
    if (k0 < Kk) aload(k0);  // prefetch next tile; latency hidden under compute
#pragma unroll
    for (int kk = 0; kk < BK; ++kk) {
      float xa[TM], yb[TN];
#pragma unroll
      for (int i = 0; i < TM; i += 4) {
        float4 x = *(const float4*)&As[kk][ty * TM + i];
        xa[i] = x.x; xa[i + 1] = x.y; xa[i + 2] = x.z; xa[i + 3] = x.w;
      }
#pragma unroll
      for (int j = 0; j < TN; j += 4) {
        float4 y = *(const float4*)&Wsh[kk][tx * TN + j];
        yb[j] = y.x; yb[j + 1] = y.y; yb[j + 2] = y.z; yb[j + 3] = y.w;
      }
#pragma unroll
      for (int i = 0; i < TM; ++i)
#pragma unroll
        for (int j = 0; j < TN; ++j) acc[i][j] = fmaf(xa[i], yb[j], acc[i][j]);
    }
    if (k0 >= Kk) break;
  }
#pragma unroll
  for (int i = 0; i < TM; ++i) {
    float* Cp = C + (size_t)(bm + ty * TM + i) * Nn + bn + tx * TN;
#pragma unroll
    for (int j = 0; j < TN; j += 4)
      *(float4*)(Cp + j) = make_float4(acc[i][j], acc[i][j + 1], acc[i][j + 2], acc[i][j + 3]);
  }
}

// ------------------------------------------------------------- RoPE in-place
__global__ void rope_apply(float* __restrict__ X, const float* __restrict__ cs,
                           const float* __restrict__ sn, int nh) {
  int id = blockIdx.x * blockDim.x + threadIdx.x;  // M * nh * 32
  int i = id & 31;
  int hm = id >> 5;
  int h = hm % nh;
  int m = hm / nh;
  int s = m & (S - 1);
  float* p = X + (size_t)m * (nh * HD) + h * HD;
  float x1 = p[i], x2 = p[i + 32];
  float c = cs[s * HD + i], si = sn[s * HD + i];
  p[i]      = x1 * c - x2 * si;
  p[i + 32] = x2 * c + x1 * si;
}

// ---------------------------------------------------- teacher flash attention
// grid (S/64, NH, B), 256 threads. fp32, causal, GQA (kv head = h/4).
// Oa may alias Q (block reads its Q slice once at start, writes same slice at end).
__global__ __launch_bounds__(256) void flash_attn(
    const float* __restrict__ Q, const float* __restrict__ K,
    const float* __restrict__ V, float* __restrict__ Oa) {
  __shared__ float qsm[HD][CHUNK + 4];   // Q^T  [d][row]
  __shared__ float kvs[HD][CHUNK + 4];   // K^T  [d][col] in S phase; V [u][v] in PV phase
  __shared__ float psm[CHUNK][CHUNK + 4];// P^T  [u][row]
  const int qt = blockIdx.x, h = blockIdx.y, b = blockIdx.z;
  const int kvh = h / NG;
  const int t = threadIdx.x;
  const int tx = t & 15, ty = t >> 4;
  const int lr = t >> 2;
  const int lc0 = (t & 3) << 4;

  {  // load Q tile transposed
    const float* qp = Q + (size_t)(b * S + qt * 64 + lr) * (NH * HD) + h * HD + lc0;
#pragma unroll
    for (int q4 = 0; q4 < 4; ++q4) {
      float4 x = *(const float4*)(qp + q4 * 4);
      qsm[lc0 + q4 * 4 + 0][lr] = x.x;
      qsm[lc0 + q4 * 4 + 1][lr] = x.y;
      qsm[lc0 + q4 * 4 + 2][lr] = x.z;
      qsm[lc0 + q4 * 4 + 3][lr] = x.w;
    }
  }
  float mrun[4], lrun[4], acc[4][4];
#pragma unroll
  for (int i = 0; i < 4; ++i) {
    mrun[i] = -INFINITY; lrun[i] = 0.f;
#pragma unroll
    for (int j = 0; j < 4; ++j) acc[i][j] = 0.f;
  }

  for (int jt = 0; jt <= qt; ++jt) {
    __syncthreads();  // protect qsm (1st iter) / previous PV reads of kvs & psm
    {  // load K tile transposed
      const float* kp = K + (size_t)(b * S + jt * 64 + lr) * (NKV * HD) + kvh * HD + lc0;
#pragma unroll
      for (int q4 = 0; q4 < 4; ++q4) {
        float4 x = *(const float4*)(kp + q4 * 4);
        kvs[lc0 + q4 * 4 + 0][lr] = x.x;
        kvs[lc0 + q4 * 4 + 1][lr] = x.y;
        kvs[lc0 + q4 * 4 + 2][lr] = x.z;
        kvs[lc0 + q4 * 4 + 3][lr] = x.w;
      }
    }
    __syncthreads();
    float sc[4][4];
#pragma unroll
    for (int i = 0; i < 4; ++i)
#pragma unroll
      for (int j = 0; j < 4; ++j) sc[i][j] = 0.f;
#pragma unroll 4
    for (int d = 0; d < HD; ++d) {
      float4 qv = *(const float4*)&qsm[d][ty * 4];
      float4 kk = *(const float4*)&kvs[d][tx * 4];
      float qa[4] = {qv.x, qv.y, qv.z, qv.w};
      float kb[4] = {kk.x, kk.y, kk.z, kk.w};
#pragma unroll
      for (int i = 0; i < 4; ++i)
#pragma unroll
        for (int j = 0; j < 4; ++j) sc[i][j] = fmaf(qa[i], kb[j], sc[i][j]);
    }
    // scale + causal mask
#pragma unroll
    for (int i = 0; i < 4; ++i)
#pragma unroll
      for (int j = 0; j < 4; ++j) {
        float v = sc[i][j] * 0.125f;
        if (jt == qt && (tx * 4 + j) > (ty * 4 + i)) v = -INFINITY;
        sc[i][j] = v;
      }
    // online softmax (row groups = 16 lanes sharing ty)
#pragma unroll
    for (int i = 0; i < 4; ++i) {
      float mloc = fmaxf(fmaxf(sc[i][0], sc[i][1]), fmaxf(sc[i][2], sc[i][3]));
#pragma unroll
      for (int mk = 1; mk <= 8; mk <<= 1) mloc = fmaxf(mloc, __shfl_xor(mloc, mk));
      float mnew = fmaxf(mrun[i], mloc);
      float sf = expf(mrun[i] - mnew);
      mrun[i] = mnew;
      float rs = 0.f;
#pragma unroll
      for (int j = 0; j < 4; ++j) {
        float e = expf(sc[i][j] - mnew);
        sc[i][j] = e;
        rs += e;
      }
#pragma unroll
      for (int mk = 1; mk <= 8; mk <<= 1) rs += __shfl_xor(rs, mk);
      lrun[i] = lrun[i] * sf + rs;
#pragma unroll
      for (int j = 0; j < 4; ++j) acc[i][j] *= sf;
    }
    // stage P transposed
#pragma unroll
    for (int i = 0; i < 4; ++i)
#pragma unroll
      for (int j = 0; j < 4; ++j) psm[tx * 4 + j][ty * 4 + i] = sc[i][j];
    __syncthreads();  // kvs (K) reads done
    {  // load V tile row-major into kvs
      const float* vp = V + (size_t)(b * S + jt * 64 + lr) * (NKV * HD) + kvh * HD + lc0;
#pragma unroll
      for (int q4 = 0; q4 < 4; ++q4) {
        float4 x = *(const float4*)(vp + q4 * 4);
        *(float4*)&kvs[lr][lc0 + q4 * 4] = x;
      }
    }
    __syncthreads();
#pragma unroll 4
    for (int u = 0; u < CHUNK; ++u) {
      float4 pv = *(const float4*)&psm[u][ty * 4];
      float4 vv = *(const float4*)&kvs[u][tx * 4];
      float pa[4] = {pv.x, pv.y, pv.z, pv.w};
      float vb[4] = {vv.x, vv.y, vv.z, vv.w};
#pragma unroll
      for (int i = 0; i < 4; ++i)
#pragma unroll
        for (int j = 0; j < 4; ++j) acc[i][j] = fmaf(pa[i], vb[j], acc[i][j]);
    }
  }
#pragma unroll
  for (int i = 0; i < 4; ++i) {
    float inv = 1.f / lrun[i];
    float* op = Oa + (size_t)(b * S + qt * 64 + ty * 4 + i) * (NH * HD) + h * HD + tx * 4;
    *(float4*)op = make_float4(acc[i][0] * inv, acc[i][1] * inv, acc[i][2] * inv, acc[i][3] * inv);
  }
}

// ------------------------------------------------- student: row softmax of 64
__global__ void softmax64(float* __restrict__ X, int nrows) {
  int row = blockIdx.x * 4 + (threadIdx.x >> 6);
  int lane = threadIdx.x & 63;
  if (row >= nrows) return;
  float* p = X + (size_t)row * 64;
  float x = p[lane];
  float mx = x;
#pragma unroll
  for (int mk = 32; mk >= 1; mk >>= 1) mx = fmaxf(mx, __shfl_xor(mx, mk));
  float e = expf(x - mx);
  float sm = e;
#pragma unroll
  for (int mk = 32; mk >= 1; mk >>= 1) sm += __shfl_xor(sm, mk);
  p[lane] = e / sm;
}

// ----------------------------------------- student: gate cumsum within chunks
// g = log_sigmoid(k_raw)/16 ; a = inclusive cumsum within chunk; A = chunk total
__global__ void gate_cumsum(const float* __restrict__ Kraw, float* __restrict__ Ac,
                            float* __restrict__ At) {
  // grid (NCHUNK, NKV, B), block 64
  int c = blockIdx.x, kv = blockIdx.y, b = blockIdx.z, d = threadIdx.x;
  float a = 0.f;
  for (int tt = 0; tt < CHUNK; ++tt) {
    int srow = c * CHUNK + tt;
    float x = Kraw[(size_t)(b * S + srow) * (NKV * HD) + kv * HD + d];
    float g = (x >= 0.f ? -log1pf(expf(-x)) : x - log1pf(expf(x))) / GATE_NORM;
    a += g;
    Ac[((size_t)(b * NKV + kv) * S + srow) * HD + d] = a;
  }
  At[((size_t)(b * NKV + kv) * NCHUNK + c) * HD + d] = a;
}

// -------------------------------- student phase 1: per-chunk outer-product T_c
// T_c[k][v] = sum_u ksm[u][k]*exp(A[k]-a[u][k]) * v[u][v]
__global__ __launch_bounds__(256) void gla_chunk_T(
    const float* __restrict__ Ks, const float* __restrict__ Vs,
    const float* __restrict__ Ac, const float* __restrict__ At,
    float* __restrict__ T) {
  __shared__ float kh[CHUNK][HD + 4];
  __shared__ float vh[CHUNK][HD + 4];
  int c = blockIdx.x, kv = blockIdx.y, b = blockIdx.z;
  int t = threadIdx.x, tx = t & 15, ty = t >> 4;
  int lr = t >> 2, lc0 = (t & 3) << 4;
  {
    int srow = c * CHUNK + lr;
    const float* kp = Ks + (size_t)(b * S + srow) * (NKV * HD) + kv * HD + lc0;
    const float* ap = Ac + ((size_t)(b * NKV + kv) * S + srow) * HD + lc0;
    const float* Ap = At + ((size_t)(b * NKV + kv) * NCHUNK + c) * HD + lc0;
    const float* vp = Vs + (size_t)(b * S + srow) * (NKV * HD) + kv * HD + lc0;
#pragma unroll
    for (int q4 = 0; q4 < 4; ++q4) {
      float4 kq = *(const float4*)(kp + q4 * 4);
      float4 aq = *(const float4*)(ap + q4 * 4);
      float4 Aq = *(const float4*)(Ap + q4 * 4);
      float4 vq = *(const float4*)(vp + q4 * 4);
      kh[lr][lc0 + q4 * 4 + 0] = kq.x * expf(Aq.x - aq.x);
      kh[lr][lc0 + q4 * 4 + 1] = kq.y * expf(Aq.y - aq.y);
      kh[lr][lc0 + q4 * 4 + 2] = kq.z * expf(Aq.z - aq.z);
      kh[lr][lc0 + q4 * 4 + 3] = kq.w * expf(Aq.w - aq.w);
      *(float4*)&vh[lr][lc0 + q4 * 4] = vq;
    }
  }
  __syncthreads();
  float acc[4][4];
#pragma unroll
  for (int i = 0; i < 4; ++i)
#pragma unroll
    for (int j = 0; j < 4; ++j) acc[i][j] = 0.f;
#pragma unroll 4
  for (int u = 0; u < CHUNK; ++u) {
    float4 kk = *(const float4*)&kh[u][ty * 4];
    float4 vv = *(const float4*)&vh[u][tx * 4];
    float ka[4] = {kk.x, kk.y, kk.z, kk.w};
    float vb[4] = {vv.x, vv.y, vv.z, vv.w};
#pragma unroll
    for (int i = 0; i < 4; ++i)
#pragma unroll
      for (int j = 0; j < 4; ++j) acc[i][j] = fmaf(ka[i], vb[j], acc[i][j]);
  }
  float* Tp = T + ((size_t)(b * NKV + kv) * NCHUNK + c) * (HD * HD);
#pragma unroll
  for (int i = 0; i < 4; ++i)
    *(float4*)&Tp[(ty * 4 + i) * HD + tx * 4] =
        make_float4(acc[i][0], acc[i][1], acc[i][2], acc[i][3]);
}

// ------------------- student phase 2: chunk scan, T_c slots become S_init(c)
__global__ void gla_scan_state(const float* __restrict__ At, float* __restrict__ T) {
  // grid (NKV, B), block 256
  int kv = blockIdx.x, b = blockIdx.y;
  int t = threadIdx.x;
  int k = t >> 2, v0 = (t & 3) << 4;
  float st[16];
#pragma unroll
  for (int i = 0; i < 16; ++i) st[i] = 0.f;
  size_t base = (size_t)(b * NKV + kv) * NCHUNK;
  for (int c = 0; c < NCHUNK; ++c) {
    float* Tp = T + (base + c) * (HD * HD) + k * HD + v0;
    float dec = expf(At[(base + c) * HD + k]);
    float tmp[16];
#pragma unroll
    for (int q = 0; q < 4; ++q) {
      float4 x = *(const float4*)(Tp + q * 4);
      tmp[q * 4 + 0] = x.x; tmp[q * 4 + 1] = x.y; tmp[q * 4 + 2] = x.z; tmp[q * 4 + 3] = x.w;
    }
#pragma unroll
    for (int q = 0; q < 4; ++q)
      *(float4*)(Tp + q * 4) =
          make_float4(st[q * 4 + 0], st[q * 4 + 1], st[q * 4 + 2], st[q * 4 + 3]);
#pragma unroll
    for (int i = 0; i < 16; ++i) st[i] = st[i] * dec + tmp[i];
  }
}

// ------------------------- student phase 3: per-chunk outputs (inter + intra)
// Go may alias Qs (block reads its Q slice once at start, writes same slice at end).
__global__ __launch_bounds__(256) void gla_output(
    const float* __restrict__ Qs, const float* __restrict__ Ks,
    const float* __restrict__ Vs, const float* __restrict__ Ac,
    const float* __restrict__ Sini, float* __restrict__ Go) {
  __shared__ float qsh[HD][CHUNK + 4];   // q~^T [d][t]
  __shared__ float ksh[HD][CHUNK + 4];   // k~^T [d][u] ; then S_init [d][v]
  __shared__ float psh[CHUNK][CHUNK + 4];// P^T  [u][t]
  int c = blockIdx.x, h = blockIdx.y, b = blockIdx.z;
  int kv = h / NG;
  int t = threadIdx.x, tx = t & 15, ty = t >> 4;
  int lr = t >> 2, lc0 = (t & 3) << 4;
  {
    int srow = c * CHUNK + lr;
    const float* qp = Qs + (size_t)(b * S + srow) * (NH * HD) + h * HD + lc0;
    const float* ap = Ac + ((size_t)(b * NKV + kv) * S + srow) * HD + lc0;
    const float* kp = Ks + (size_t)(b * S + srow) * (NKV * HD) + kv * HD + lc0;
#pragma unroll
    for (int q4 = 0; q4 < 4; ++q4) {
      float4 qv = *(const float4*)(qp + q4 * 4);
      float4 av = *(const float4*)(ap + q4 * 4);
      float4 kq = *(const float4*)(kp + q4 * 4);
      float e0 = expf(av.x), e1 = expf(av.y), e2 = expf(av.z), e3 = expf(av.w);
      qsh[lc0 + q4 * 4 + 0][lr] = qv.x * e0;
      qsh[lc0 + q4 * 4 + 1][lr] = qv.y * e1;
      qsh[lc0 + q4 * 4 + 2][lr] = qv.z * e2;
      qsh[lc0 + q4 * 4 + 3][lr] = qv.w * e3;
      ksh[lc0 + q4 * 4 + 0][lr] = kq.x / e0;
      ksh[lc0 + q4 * 4 + 1][lr] = kq.y / e1;
      ksh[lc0 + q4 * 4 + 2][lr] = kq.z / e2;
      ksh[lc0 + q4 * 4 + 3][lr] = kq.w / e3;
    }
  }
  __syncthreads();
  // P[t][u] = (q~_t . k~_u), masked u<=t
  float p[4][4];
#pragma unroll
  for (int i = 0; i < 4; ++i)
#pragma unroll
    for (int j = 0; j < 4; ++j) p[i][j] = 0.f;
#pragma unroll 4
  for (int d = 0; d < HD; ++d) {
    float4 qv = *(const float4*)&qsh[d][ty * 4];
    float4 kq = *(const float4*)&ksh[d][tx * 4];
    float qa[4] = {qv.x, qv.y, qv.z, qv.w};
    float kb[4] = {kq.x, kq.y, kq.z, kq.w};
#pragma unroll
    for (int i = 0; i < 4; ++i)
#pragma unroll
      for (int j = 0; j < 4; ++j) p[i][j] = fmaf(qa[i], kb[j], p[i][j]);
  }
#pragma unroll
  for (int i = 0; i < 4; ++i)
#pragma unroll
    for (int j = 0; j < 4; ++j) {
      if (tx * 4 + j > ty * 4 + i) p[i][j] = 0.f;
      psh[tx * 4 + j][ty * 4 + i] = p[i][j];
    }
  __syncthreads();  // ksh (k~) reads done
  {  // load S_init row-major into ksh
    const float* Sp = Sini + ((size_t)(b * NKV + kv) * NCHUNK + c) * (HD * HD) + lr * HD + lc0;
#pragma unroll
    for (int q4 = 0; q4 < 4; ++q4)
      *(float4*)&ksh[lr][lc0 + q4 * 4] = *(const float4*)(Sp + q4 * 4);
  }
  __syncthreads();
  // inter: o[t][v] = sum_d q~[t][d] * S_init[d][v]
  float o[4][4];
#pragma unroll
  for (int i = 0; i < 4; ++i)
#pragma unroll
    for (int j = 0; j < 4; ++j) o[i][j] = 0.f;
#pragma unroll 4
  for (int d = 0; d < HD; ++d) {
    float4 qv = *(const float4*)&qsh[d][ty * 4];
    float4 sv = *(const float4*)&ksh[d][tx * 4];
    float qa[4] = {qv.x, qv.y, qv.z, qv.w};
    float sb[4] = {sv.x, sv.y, sv.z, sv.w};
#pragma unroll
    for (int i = 0; i < 4; ++i)
#pragma unroll
      for (int j = 0; j < 4; ++j) o[i][j] = fmaf(qa[i], sb[j], o[i][j]);
  }
  __syncthreads();  // qsh reads done
  {  // load V row-major into qsh
    const float* vp = Vs + (size_t)(b * S + c * CHUNK + lr) * (NKV * HD) + kv * HD + lc0;
#pragma unroll
    for (int q4 = 0; q4 < 4; ++q4)
      *(float4*)&qsh[lr][lc0 + q4 * 4] = *(const float4*)(vp + q4 * 4);
  }
  __syncthreads();
  // intra: o += sum_u P^T[u][t] * V[u][v]
#pragma unroll 4
  for (int u = 0; u < CHUNK; ++u) {
    float4 pv = *(const float4*)&psh[u][ty * 4];
    float4 vv = *(const float4*)&qsh[u][tx * 4];
    float pa[4] = {pv.x, pv.y, pv.z, pv.w};
    float vb[4] = {vv.x, vv.y, vv.z, vv.w};
#pragma unroll
    for (int i = 0; i < 4; ++i)
#pragma unroll
      for (int j = 0; j < 4; ++j) o[i][j] = fmaf(pa[i], vb[j], o[i][j]);
  }
#pragma unroll
  for (int i = 0; i < 4; ++i) {
    float* gp = Go + (size_t)(b * S + c * CHUNK + ty * 4 + i) * (NH * HD) + h * HD + tx * 4;
    *(float4*)gp = make_float4(o[i][0], o[i][1], o[i][2], o[i][3]);
  }
}

}  // namespace

extern "C" void kernel_launch(void* const* d_in, const int* in_sizes, int n_in,
                              void* d_out, int out_size, void* d_ws, size_t ws_size,
                              hipStream_t stream) {
  (void)in_sizes; (void)n_in; (void)out_size; (void)ws_size;
  const float* hs  = (const float*)d_in[0];
  const float* wq  = (const float*)d_in[1];
  const float* wk  = (const float*)d_in[2];
  const float* wv  = (const float*)d_in[3];
  const float* wo  = (const float*)d_in[4];
  const float* wqs = (const float*)d_in[5];
  const float* wks = (const float*)d_in[6];
  const float* wvs = (const float*)d_in[7];
  const float* wos = (const float*)d_in[8];
  float* out = (float*)d_out;
  float* ws  = (float*)d_ws;

  float* cs = ws + OFS_COS;
  float* sn = ws + OFS_SIN;
  float* qb = ws + OFS_Q;
  float* kb = ws + OFS_K;
  float* vb = ws + OFS_V;
  float* ac = ws + OFS_AC;
  float* at = ws + OFS_AT;
  float* Tb = ws + OFS_T;

  // ---- RoPE tables
  rope_table<<<(S * (HD / 2)) / 256, 256, 0, stream>>>(cs, sn);

  // ---- teacher projections
  gemm_nt<128, 128, 8, 8, 256><<<dim3(M / 128, (NH * HD) / 128), 256, 0, stream>>>(hs, wq, qb, M, NH * HD, H);
  gemm_nt<64, 64, 4, 4, 256><<<dim3(M / 64, (NKV * HD) / 64), 256, 0, stream>>>(hs, wk, kb, M, NKV * HD, H);
  gemm_nt<64, 64, 4, 4, 256><<<dim3(M / 64, (NKV * HD) / 64), 256, 0, stream>>>(hs, wv, vb, M, NKV * HD, H);
  rope_apply<<<(M * NH * 32) / 256, 256, 0, stream>>>(qb, cs, sn, NH);
  rope_apply<<<(M * NKV * 32) / 256, 256, 0, stream>>>(kb, cs, sn, NKV);
  flash_attn<<<dim3(S / 64, NH, B), 256, 0, stream>>>(qb, kb, vb, qb);  // in-place over Q
  gemm_nt<128, 128, 8, 8, 256><<<dim3(M / 128, (NH * HD) / 128), 256, 0, stream>>>(qb, wo, out, M, NH * HD, H);

  // ---- student projections (reuse teacher buffers; stream-serial)
  gemm_nt<128, 128, 8, 8, 256><<<dim3(M / 128, (NH * HD) / 128), 256, 0, stream>>>(hs, wqs, qb, M, NH * HD, H);
  gemm_nt<64, 64, 4, 4, 256><<<dim3(M / 64, (NKV * HD) / 64), 256, 0, stream>>>(hs, wks, kb, M, NKV * HD, H);
  gemm_nt<64, 64, 4, 4, 256><<<dim3(M / 64, (NKV * HD) / 64), 256, 0, stream>>>(hs, wvs, vb, M, NKV * HD, H);

  // gates from RAW k, then softmax q/k in place
  gate_cumsum<<<dim3(NCHUNK, NKV, B), 64, 0, stream>>>(kb, ac, at);
  softmax64<<<(M * NH) / 4, 256, 0, stream>>>(qb, M * NH);
  softmax64<<<(M * NKV) / 4, 256, 0, stream>>>(kb, M * NKV);

  // chunked GLA
  gla_chunk_T<<<dim3(NCHUNK, NKV, B), 256, 0, stream>>>(kb, vb, ac, at, Tb);
  gla_scan_state<<<dim3(NKV, B), 256, 0, stream>>>(at, Tb);
  gla_output<<<dim3(NCHUNK, NH, B), 256, 0, stream>>>(qb, kb, vb, ac, Tb, qb);  // in-place over Q

  // student output projection
  gemm_nt<128, 128, 8, 8, 256><<<dim3(M / 128, (NH * HD) / 128), 256, 0, stream>>>(qb, wos, out + (size_t)M * (NH * HD), M, NH * HD, H);
}

// Round 5
// 1954.935 us; speedup vs baseline: 1.7481x; 1.7481x over previous
//
#include <hip/hip_runtime.h>
#include <math.h>

namespace {

constexpr int B = 2, S = 2048, NH = 32, NKV = 8, HD = 64, NG = 4;
constexpr int M = B * S;                      // 4096 rows
constexpr int H = 2048;                       // hidden (= K dim of projections)
constexpr int CHUNK = 64, NCHUNK = S / CHUNK; // 32 chunks
constexpr float GATE_NORM = 16.0f;

typedef __attribute__((ext_vector_type(8))) short short8;   // 8 bf16 (4 VGPRs)
typedef __attribute__((ext_vector_type(4))) float f32x4;    // MFMA accum

// ---- workspace layout (floats), 17,072,128 floats = 68.3 MB (proven to fit).
constexpr size_t OFS_COS = 0;
constexpr size_t OFS_SIN = OFS_COS + (size_t)S * HD;
constexpr size_t OFS_Q   = OFS_SIN + (size_t)S * HD;                    // q; overwritten by attn/gla out
constexpr size_t OFS_K   = OFS_Q   + (size_t)M * (NH * HD);
constexpr size_t OFS_V   = OFS_K   + (size_t)M * (NKV * HD);
constexpr size_t OFS_AC  = OFS_V   + (size_t)M * (NKV * HD);
constexpr size_t OFS_AT  = OFS_AC  + (size_t)B * NKV * S * HD;
constexpr size_t OFS_T   = OFS_AT  + (size_t)B * NKV * NCHUNK * HD;

// ---------------------------------------------------------------- RoPE tables
__global__ void rope_table(float* __restrict__ cs, float* __restrict__ sn) {
  int id = blockIdx.x * blockDim.x + threadIdx.x;  // S * 32
  if (id >= S * (HD / 2)) return;
  int s = id >> 5, i = id & 31;
  double inv = exp(-(double)(2 * i) / 64.0 * log(500000.0));
  float f = (float)s * (float)inv;
  float c = cosf(f), si = sinf(f);
  cs[s * HD + i] = c;  cs[s * HD + i + 32] = c;
  sn[s * HD + i] = si; sn[s * HD + i + 32] = si;
}

// ----------------------------------------------- split-bf16 MFMA GEMM, C=A*W^T
// A [Mm,Kk] fp32 row-major, W [Nn,Kk] fp32 row-major, C [Mm,Nn] fp32.
// a = ah + al (bf16 truncation split); A*W^T ~= ah*bh + ah*bl + al*bh
// (drops al*bl ~ 2^-16 relative). LDS holds MFMA fragments contiguously:
// frag f (= mfgroup*64 + lane): elems X[fgrp*16 + (lane&15)][(lane>>4)*8 + e].
// Wave-contiguous ds_read_b128 => conflict-free reads AND writes.
template <int BM, int BN, int WR, int WC>
__global__ __launch_bounds__(256) void gemm_mfma(
    const float* __restrict__ A, const float* __restrict__ W,
    float* __restrict__ C, int Mm, int Nn, int Kk) {
  constexpr int BK = 32;
  constexpr int MF = BM / 16, NF = BN / 16;     // 16-row/col frag groups
  constexpr int MFR = MF / WR, NFR = NF / WC;   // frag groups per wave
  constexpr int NA = MF * 64, NB = NF * 64;     // total frags per tile
  constexpr int CA = NA / 256, CB = NB / 256;   // frags staged per thread
  static_assert(CA >= 1 && CB >= 1 && MF == WR * MFR && NF == WC * NFR, "cfg");
  __shared__ short Ah[NA * 8], Al[NA * 8], Bh[NB * 8], Bl[NB * 8];

  const int t = threadIdx.x;
  const int l = t & 63, w = t >> 6;
  const int wr = w / WC, wc = w % WC;
  const int bm = blockIdx.x * BM, bn = blockIdx.y * BN;

  // per-thread staged-fragment global base pointers
  const float* ga[CA];
  const float* gb[CB];
#pragma unroll
  for (int i = 0; i < CA; ++i) {
    int f = t + i * 256, lf = f & 63;
    int row = (f >> 6) * 16 + (lf & 15), ks = (lf >> 4) * 8;
    ga[i] = A + (size_t)(bm + row) * Kk + ks;
  }
#pragma unroll
  for (int i = 0; i < CB; ++i) {
    int f = t + i * 256, lf = f & 63;
    int col = (f >> 6) * 16 + (lf & 15), ks = (lf >> 4) * 8;
    gb[i] = W + (size_t)(bn + col) * Kk + ks;
  }

  float4 ra[CA * 2], rb[CB * 2];
  auto gload = [&](int k0) {
#pragma unroll
    for (int i = 0; i < CA; ++i) {
      ra[2 * i]     = *(const float4*)(ga[i] + k0);
      ra[2 * i + 1] = *(const float4*)(ga[i] + k0 + 4);
    }
#pragma unroll
    for (int i = 0; i < CB; ++i) {
      rb[2 * i]     = *(const float4*)(gb[i] + k0);
      rb[2 * i + 1] = *(const float4*)(gb[i] + k0 + 4);
    }
  };

  // truncation split of 8 floats -> packed hi/lo (4 uints each)
  auto split8 = [](float4 x, float4 y, uint* oh, uint* ol) {
    float v0[4] = {x.x, x.y, x.z, x.w};
    float v1[4] = {y.x, y.y, y.z, y.w};
    float v[8];
#pragma unroll
    for (int p = 0; p < 4; ++p) { v[p] = v0[p]; v[p + 4] = v1[p]; }
#pragma unroll
    for (int p = 0; p < 4; ++p) {
      uint u0 = __float_as_uint(v[2 * p]), u1 = __float_as_uint(v[2 * p + 1]);
      float h0 = __uint_as_float(u0 & 0xFFFF0000u);
      float h1 = __uint_as_float(u1 & 0xFFFF0000u);
      uint l0 = __float_as_uint(v[2 * p] - h0), l1 = __float_as_uint(v[2 * p + 1] - h1);
      oh[p] = (u0 >> 16) | (u1 & 0xFFFF0000u);
      ol[p] = (l0 >> 16) | (l1 & 0xFFFF0000u);
    }
  };

  auto cvt_store = [&]() {
#pragma unroll
    for (int i = 0; i < CA; ++i) {
      int f = t + i * 256;
      uint oh[4], ol[4];
      split8(ra[2 * i], ra[2 * i + 1], oh, ol);
      *(int4*)&Ah[f * 8] = make_int4(oh[0], oh[1], oh[2], oh[3]);
      *(int4*)&Al[f * 8] = make_int4(ol[0], ol[1], ol[2], ol[3]);
    }
#pragma unroll
    for (int i = 0; i < CB; ++i) {
      int f = t + i * 256;
      uint oh[4], ol[4];
      split8(rb[2 * i], rb[2 * i + 1], oh, ol);
      *(int4*)&Bh[f * 8] = make_int4(oh[0], oh[1], oh[2], oh[3]);
      *(int4*)&Bl[f * 8] = make_int4(ol[0], ol[1], ol[2], ol[3]);
    }
  };

  f32x4 acc[MFR][NFR] = {};
  gload(0);
  for (int k0 = 0;;) {
    __syncthreads();   // previous tile's LDS reads complete
    cvt_store();
    __syncthreads();
    k0 += BK;
    bool more = k0 < Kk;
    if (more) gload(k0);  // prefetch next fp32 tile under compute

    short8 ah[MFR], al[MFR];
#pragma unroll
    for (int m = 0; m < MFR; ++m) {
      ah[m] = *(const short8*)&Ah[((wr * MFR + m) * 64 + l) * 8];
      al[m] = *(const short8*)&Al[((wr * MFR + m) * 64 + l) * 8];
    }
#pragma unroll
    for (int n = 0; n < NFR; ++n) {
      short8 bh = *(const short8*)&Bh[((wc * NFR + n) * 64 + l) * 8];
      short8 bl = *(const short8*)&Bl[((wc * NFR + n) * 64 + l) * 8];
#pragma unroll
      for (int m = 0; m < MFR; ++m) {
        acc[m][n] = __builtin_amdgcn_mfma_f32_16x16x32_bf16(ah[m], bh, acc[m][n], 0, 0, 0);
        acc[m][n] = __builtin_amdgcn_mfma_f32_16x16x32_bf16(ah[m], bl, acc[m][n], 0, 0, 0);
        acc[m][n] = __builtin_amdgcn_mfma_f32_16x16x32_bf16(al[m], bh, acc[m][n], 0, 0, 0);
      }
    }
    if (!more) break;
  }

  // C/D layout: col = lane&15, row = (lane>>4)*4 + reg  [m89-verified]
#pragma unroll
  for (int m = 0; m < MFR; ++m)
#pragma unroll
    for (int n = 0; n < NFR; ++n) {
      int col = bn + (wc * NFR + n) * 16 + (l & 15);
      int row0 = bm + (wr * MFR + m) * 16 + (l >> 4) * 4;
#pragma unroll
      for (int i = 0; i < 4; ++i)
        C[(size_t)(row0 + i) * Nn + col] = acc[m][n][i];
    }
}

// ------------------------------------------------------------- RoPE in-place
__global__ void rope_apply(float* __restrict__ X, const float* __restrict__ cs,
                           const float* __restrict__ sn, int nh) {
  int id = blockIdx.x * blockDim.x + threadIdx.x;  // M * nh * 32
  int i = id & 31;
  int hm = id >> 5;
  int h = hm % nh;
  int m = hm / nh;
  int s = m & (S - 1);
  float* p = X + (size_t)m * (nh * HD) + h * HD;
  float x1 = p[i], x2 = p[i + 32];
  float c = cs[s * HD + i], si = sn[s * HD + i];
  p[i]      = x1 * c - x2 * si;
  p[i + 32] = x2 * c + x1 * si;
}

// ---------------------------------------------------- teacher flash attention
// grid (S/64, NH, B), 256 threads. fp32, causal, GQA (kv head = h/4).
// qt reversed: heaviest q-tiles dispatch first (work ~ qt+1) -> better makespan.
// Oa may alias Q (block reads its Q slice once at start, writes same slice at end).
__global__ __launch_bounds__(256) void flash_attn(
    const float* __restrict__ Q, const float* __restrict__ K,
    const float* __restrict__ V, float* __restrict__ Oa) {
  __shared__ float qsm[HD][CHUNK + 4];
  __shared__ float kvs[HD][CHUNK + 4];
  __shared__ float psm[CHUNK][CHUNK + 4];
  const int qt = (int)gridDim.x - 1 - (int)blockIdx.x;
  const int h = blockIdx.y, b = blockIdx.z;
  const int kvh = h / NG;
  const int t = threadIdx.x;
  const int tx = t & 15, ty = t >> 4;
  const int lr = t >> 2;
  const int lc0 = (t & 3) << 4;

  {  // load Q tile transposed
    const float* qp = Q + (size_t)(b * S + qt * 64 + lr) * (NH * HD) + h * HD + lc0;
#pragma unroll
    for (int q4 = 0; q4 < 4; ++q4) {
      float4 x = *(const float4*)(qp + q4 * 4);
      qsm[lc0 + q4 * 4 + 0][lr] = x.x;
      qsm[lc0 + q4 * 4 + 1][lr] = x.y;
      qsm[lc0 + q4 * 4 + 2][lr] = x.z;
      qsm[lc0 + q4 * 4 + 3][lr] = x.w;
    }
  }
  float mrun[4], lrun[4], acc[4][4];
#pragma unroll
  for (int i = 0; i < 4; ++i) {
    mrun[i] = -INFINITY; lrun[i] = 0.f;
#pragma unroll
    for (int j = 0; j < 4; ++j) acc[i][j] = 0.f;
  }

  for (int jt = 0; jt <= qt; ++jt) {
    __syncthreads();
    {  // load K tile transposed
      const float* kp = K + (size_t)(b * S + jt * 64 + lr) * (NKV * HD) + kvh * HD + lc0;
#pragma unroll
      for (int q4 = 0; q4 < 4; ++q4) {
        float4 x = *(const float4*)(kp + q4 * 4);
        kvs[lc0 + q4 * 4 + 0][lr] = x.x;
        kvs[lc0 + q4 * 4 + 1][lr] = x.y;
        kvs[lc0 + q4 * 4 + 2][lr] = x.z;
        kvs[lc0 + q4 * 4 + 3][lr] = x.w;
      }
    }
    __syncthreads();
    float sc[4][4];
#pragma unroll
    for (int i = 0; i < 4; ++i)
#pragma unroll
      for (int j = 0; j < 4; ++j) sc[i][j] = 0.f;
#pragma unroll 4
    for (int d = 0; d < HD; ++d) {
      float4 qv = *(const float4*)&qsm[d][ty * 4];
      float4 kk = *(const float4*)&kvs[d][tx * 4];
      float qa[4] = {qv.x, qv.y, qv.z, qv.w};
      float kb[4] = {kk.x, kk.y, kk.z, kk.w};
#pragma unroll
      for (int i = 0; i < 4; ++i)
#pragma unroll
        for (int j = 0; j < 4; ++j) sc[i][j] = fmaf(qa[i], kb[j], sc[i][j]);
    }
#pragma unroll
    for (int i = 0; i < 4; ++i)
#pragma unroll
      for (int j = 0; j < 4; ++j) {
        float v = sc[i][j] * 0.125f;
        if (jt == qt && (tx * 4 + j) > (ty * 4 + i)) v = -INFINITY;
        sc[i][j] = v;
      }
#pragma unroll
    for (int i = 0; i < 4; ++i) {
      float mloc = fmaxf(fmaxf(sc[i][0], sc[i][1]), fmaxf(sc[i][2], sc[i][3]));
#pragma unroll
      for (int mk = 1; mk <= 8; mk <<= 1) mloc = fmaxf(mloc, __shfl_xor(mloc, mk));
      float mnew = fmaxf(mrun[i], mloc);
      float sf = expf(mrun[i] - mnew);
      mrun[i] = mnew;
      float rs = 0.f;
#pragma unroll
      for (int j = 0; j < 4; ++j) {
        float e = expf(sc[i][j] - mnew);
        sc[i][j] = e;
        rs += e;
      }
#pragma unroll
      for (int mk = 1; mk <= 8; mk <<= 1) rs += __shfl_xor(rs, mk);
      lrun[i] = lrun[i] * sf + rs;
#pragma unroll
      for (int j = 0; j < 4; ++j) acc[i][j] *= sf;
    }
#pragma unroll
    for (int i = 0; i < 4; ++i)
#pragma unroll
      for (int j = 0; j < 4; ++j) psm[tx * 4 + j][ty * 4 + i] = sc[i][j];
    __syncthreads();
    {  // load V tile row-major into kvs
      const float* vp = V + (size_t)(b * S + jt * 64 + lr) * (NKV * HD) + kvh * HD + lc0;
#pragma unroll
      for (int q4 = 0; q4 < 4; ++q4) {
        float4 x = *(const float4*)(vp + q4 * 4);
        *(float4*)&kvs[lr][lc0 + q4 * 4] = x;
      }
    }
    __syncthreads();
#pragma unroll 4
    for (int u = 0; u < CHUNK; ++u) {
      float4 pv = *(const float4*)&psm[u][ty * 4];
      float4 vv = *(const float4*)&kvs[u][tx * 4];
      float pa[4] = {pv.x, pv.y, pv.z, pv.w};
      float vb[4] = {vv.x, vv.y, vv.z, vv.w};
#pragma unroll
      for (int i = 0; i < 4; ++i)
#pragma unroll
        for (int j = 0; j < 4; ++j) acc[i][j] = fmaf(pa[i], vb[j], acc[i][j]);
    }
  }
#pragma unroll
  for (int i = 0; i < 4; ++i) {
    float inv = 1.f / lrun[i];
    float* op = Oa + (size_t)(b * S + qt * 64 + ty * 4 + i) * (NH * HD) + h * HD + tx * 4;
    *(float4*)op = make_float4(acc[i][0] * inv, acc[i][1] * inv, acc[i][2] * inv, acc[i][3] * inv);
  }
}

// ------------------------------------------------- student: row softmax of 64
__global__ void softmax64(float* __restrict__ X, int nrows) {
  int row = blockIdx.x * 4 + (threadIdx.x >> 6);
  int lane = threadIdx.x & 63;
  if (row >= nrows) return;
  float* p = X + (size_t)row * 64;
  float x = p[lane];
  float mx = x;
#pragma unroll
  for (int mk = 32; mk >= 1; mk >>= 1) mx = fmaxf(mx, __shfl_xor(mx, mk));
  float e = expf(x - mx);
  float sm = e;
#pragma unroll
  for (int mk = 32; mk >= 1; mk >>= 1) sm += __shfl_xor(sm, mk);
  p[lane] = e / sm;
}

// ----------------------------------------- student: gate cumsum within chunks
__global__ void gate_cumsum(const float* __restrict__ Kraw, float* __restrict__ Ac,
                            float* __restrict__ At) {
  int c = blockIdx.x, kv = blockIdx.y, b = blockIdx.z, d = threadIdx.x;
  float a = 0.f;
  for (int tt = 0; tt < CHUNK; ++tt) {
    int srow = c * CHUNK + tt;
    float x = Kraw[(size_t)(b * S + srow) * (NKV * HD) + kv * HD + d];
    float g = (x >= 0.f ? -log1pf(expf(-x)) : x - log1pf(expf(x))) / GATE_NORM;
    a += g;
    Ac[((size_t)(b * NKV + kv) * S + srow) * HD + d] = a;
  }
  At[((size_t)(b * NKV + kv) * NCHUNK + c) * HD + d] = a;
}

// -------------------------------- student phase 1: per-chunk outer-product T_c
__global__ __launch_bounds__(256) void gla_chunk_T(
    const float* __restrict__ Ks, const float* __restrict__ Vs,
    const float* __restrict__ Ac, const float* __restrict__ At,
    float* __restrict__ T) {
  __shared__ float kh[CHUNK][HD + 4];
  __shared__ float vh[CHUNK][HD + 4];
  int c = blockIdx.x, kv = blockIdx.y, b = blockIdx.z;
  int t = threadIdx.x, tx = t & 15, ty = t >> 4;
  int lr = t >> 2, lc0 = (t & 3) << 4;
  {
    int srow = c * CHUNK + lr;
    const float* kp = Ks + (size_t)(b * S + srow) * (NKV * HD) + kv * HD + lc0;
    const float* ap = Ac + ((size_t)(b * NKV + kv) * S + srow) * HD + lc0;
    const float* Ap = At + ((size_t)(b * NKV + kv) * NCHUNK + c) * HD + lc0;
    const float* vp = Vs + (size_t)(b * S + srow) * (NKV * HD) + kv * HD + lc0;
#pragma unroll
    for (int q4 = 0; q4 < 4; ++q4) {
      float4 kq = *(const float4*)(kp + q4 * 4);
      float4 aq = *(const float4*)(ap + q4 * 4);
      float4 Aq = *(const float4*)(Ap + q4 * 4);
      float4 vq = *(const float4*)(vp + q4 * 4);
      kh[lr][lc0 + q4 * 4 + 0] = kq.x * expf(Aq.x - aq.x);
      kh[lr][lc0 + q4 * 4 + 1] = kq.y * expf(Aq.y - aq.y);
      kh[lr][lc0 + q4 * 4 + 2] = kq.z * expf(Aq.z - aq.z);
      kh[lr][lc0 + q4 * 4 + 3] = kq.w * expf(Aq.w - aq.w);
      *(float4*)&vh[lr][lc0 + q4 * 4] = vq;
    }
  }
  __syncthreads();
  float acc[4][4];
#pragma unroll
  for (int i = 0; i < 4; ++i)
#pragma unroll
    for (int j = 0; j < 4; ++j) acc[i][j] = 0.f;
#pragma unroll 4
  for (int u = 0; u < CHUNK; ++u) {
    float4 kk = *(const float4*)&kh[u][ty * 4];
    float4 vv = *(const float4*)&vh[u][tx * 4];
    float ka[4] = {kk.x, kk.y, kk.z, kk.w};
    float vb[4] = {vv.x, vv.y, vv.z, vv.w};
#pragma unroll
    for (int i = 0; i < 4; ++i)
#pragma unroll
      for (int j = 0; j < 4; ++j) acc[i][j] = fmaf(ka[i], vb[j], acc[i][j]);
  }
  float* Tp = T + ((size_t)(b * NKV + kv) * NCHUNK + c) * (HD * HD);
#pragma unroll
  for (int i = 0; i < 4; ++i)
    *(float4*)&Tp[(ty * 4 + i) * HD + tx * 4] =
        make_float4(acc[i][0], acc[i][1], acc[i][2], acc[i][3]);
}

// ------------------- student phase 2: chunk scan, T_c slots become S_init(c)
__global__ void gla_scan_state(const float* __restrict__ At, float* __restrict__ T) {
  int kv = blockIdx.x, b = blockIdx.y;
  int t = threadIdx.x;
  int k = t >> 2, v0 = (t & 3) << 4;
  float st[16];
#pragma unroll
  for (int i = 0; i < 16; ++i) st[i] = 0.f;
  size_t base = (size_t)(b * NKV + kv) * NCHUNK;
  for (int c = 0; c < NCHUNK; ++c) {
    float* Tp = T + (base + c) * (HD * HD) + k * HD + v0;
    float dec = expf(At[(base + c) * HD + k]);
    float tmp[16];
#pragma unroll
    for (int q = 0; q < 4; ++q) {
      float4 x = *(const float4*)(Tp + q * 4);
      tmp[q * 4 + 0] = x.x; tmp[q * 4 + 1] = x.y; tmp[q * 4 + 2] = x.z; tmp[q * 4 + 3] = x.w;
    }
#pragma unroll
    for (int q = 0; q < 4; ++q)
      *(float4*)(Tp + q * 4) =
          make_float4(st[q * 4 + 0], st[q * 4 + 1], st[q * 4 + 2], st[q * 4 + 3]);
#pragma unroll
    for (int i = 0; i < 16; ++i) st[i] = st[i] * dec + tmp[i];
  }
}

// ------------------------- student phase 3: per-chunk outputs (inter + intra)
__global__ __launch_bounds__(256) void gla_output(
    const float* __restrict__ Qs, const float* __restrict__ Ks,
    const float* __restrict__ Vs, const float* __restrict__ Ac,
    const float* __restrict__ Sini, float* __restrict__ Go) {
  __shared__ float qsh[HD][CHUNK + 4];
  __shared__ float ksh[HD][CHUNK + 4];
  __shared__ float psh[CHUNK][CHUNK + 4];
  int c = blockIdx.x, h = blockIdx.y, b = blockIdx.z;
  int kv = h / NG;
  int t = threadIdx.x, tx = t & 15, ty = t >> 4;
  int lr = t >> 2, lc0 = (t & 3) << 4;
  {
    int srow = c * CHUNK + lr;
    const float* qp = Qs + (size_t)(b * S + srow) * (NH * HD) + h * HD + lc0;
    const float* ap = Ac + ((size_t)(b * NKV + kv) * S + srow) * HD + lc0;
    const float* kp = Ks + (size_t)(b * S + srow) * (NKV * HD) + kv * HD + lc0;
#pragma unroll
    for (int q4 = 0; q4 < 4; ++q4) {
      float4 qv = *(const float4*)(qp + q4 * 4);
      float4 av = *(const float4*)(ap + q4 * 4);
      float4 kq = *(const float4*)(kp + q4 * 4);
      float e0 = expf(av.x), e1 = expf(av.y), e2 = expf(av.z), e3 = expf(av.w);
      qsh[lc0 + q4 * 4 + 0][lr] = qv.x * e0;
      qsh[lc0 + q4 * 4 + 1][lr] = qv.y * e1;
      qsh[lc0 + q4 * 4 + 2][lr] = qv.z * e2;
      qsh[lc0 + q4 * 4 + 3][lr] = qv.w * e3;
      ksh[lc0 + q4 * 4 + 0][lr] = kq.x / e0;
      ksh[lc0 + q4 * 4 + 1][lr] = kq.y / e1;
      ksh[lc0 + q4 * 4 + 2][lr] = kq.z / e2;
      ksh[lc0 + q4 * 4 + 3][lr] = kq.w / e3;
    }
  }
  __syncthreads();
  float p[4][4];
#pragma unroll
  for (int i = 0; i < 4; ++i)
#pragma unroll
    for (int j = 0; j < 4; ++j) p[i][j] = 0.f;
#pragma unroll 4
  for (int d = 0; d < HD; ++d) {
    float4 qv = *(const float4*)&qsh[d][ty * 4];
    float4 kq = *(const float4*)&ksh[d][tx * 4];
    float qa[4] = {qv.x, qv.y, qv.z, qv.w};
    float kb[4] = {kq.x, kq.y, kq.z, kq.w};
#pragma unroll
    for (int i = 0; i < 4; ++i)
#pragma unroll
      for (int j = 0; j < 4; ++j) p[i][j] = fmaf(qa[i], kb[j], p[i][j]);
  }
#pragma unroll
  for (int i = 0; i < 4; ++i)
#pragma unroll
    for (int j = 0; j < 4; ++j) {
      if (tx * 4 + j > ty * 4 + i) p[i][j] = 0.f;
      psh[tx * 4 + j][ty * 4 + i] = p[i][j];
    }
  __syncthreads();
  {
    const float* Sp = Sini + ((size_t)(b * NKV + kv) * NCHUNK + c) * (HD * HD) + lr * HD + lc0;
#pragma unroll
    for (int q4 = 0; q4 < 4; ++q4)
      *(float4*)&ksh[lr][lc0 + q4 * 4] = *(const float4*)(Sp + q4 * 4);
  }
  __syncthreads();
  float o[4][4];
#pragma unroll
  for (int i = 0; i < 4; ++i)
#pragma unroll
    for (int j = 0; j < 4; ++j) o[i][j] = 0.f;
#pragma unroll 4
  for (int d = 0; d < HD; ++d) {
    float4 qv = *(const float4*)&qsh[d][ty * 4];
    float4 sv = *(const float4*)&ksh[d][tx * 4];
    float qa[4] = {qv.x, qv.y, qv.z, qv.w};
    float sb[4] = {sv.x, sv.y, sv.z, sv.w};
#pragma unroll
    for (int i = 0; i < 4; ++i)
#pragma unroll
      for (int j = 0; j < 4; ++j) o[i][j] = fmaf(qa[i], sb[j], o[i][j]);
  }
  __syncthreads();
  {
    const float* vp = Vs + (size_t)(b * S + c * CHUNK + lr) * (NKV * HD) + kv * HD + lc0;
#pragma unroll
    for (int q4 = 0; q4 < 4; ++q4)
      *(float4*)&qsh[lr][lc0 + q4 * 4] = *(const float4*)(vp + q4 * 4);
  }
  __syncthreads();
#pragma unroll 4
  for (int u = 0; u < CHUNK; ++u) {
    float4 pv = *(const float4*)&psh[u][ty * 4];
    float4 vv = *(const float4*)&qsh[u][tx * 4];
    float pa[4] = {pv.x, pv.y, pv.z, pv.w};
    float vb[4] = {vv.x, vv.y, vv.z, vv.w};
#pragma unroll
    for (int i = 0; i < 4; ++i)
#pragma unroll
      for (int j = 0; j < 4; ++j) o[i][j] = fmaf(pa[i], vb[j], o[i][j]);
  }
#pragma unroll
  for (int i = 0; i < 4; ++i) {
    float* gp = Go + (size_t)(b * S + c * CHUNK + ty * 4 + i) * (NH * HD) + h * HD + tx * 4;
    *(float4*)gp = make_float4(o[i][0], o[i][1], o[i][2], o[i][3]);
  }
}

}  // namespace

extern "C" void kernel_launch(void* const* d_in, const int* in_sizes, int n_in,
                              void* d_out, int out_size, void* d_ws, size_t ws_size,
                              hipStream_t stream) {
  (void)in_sizes; (void)n_in; (void)out_size; (void)ws_size;
  const float* hs  = (const float*)d_in[0];
  const float* wq  = (const float*)d_in[1];
  const float* wk  = (const float*)d_in[2];
  const float* wv  = (const float*)d_in[3];
  const float* wo  = (const float*)d_in[4];
  const float* wqs = (const float*)d_in[5];
  const float* wks = (const float*)d_in[6];
  const float* wvs = (const float*)d_in[7];
  const float* wos = (const float*)d_in[8];
  float* out = (float*)d_out;
  float* ws  = (float*)d_ws;

  float* cs = ws + OFS_COS;
  float* sn = ws + OFS_SIN;
  float* qb = ws + OFS_Q;
  float* kb = ws + OFS_K;
  float* vb = ws + OFS_V;
  float* ac = ws + OFS_AC;
  float* at = ws + OFS_AT;
  float* Tb = ws + OFS_T;

  rope_table<<<(S * (HD / 2)) / 256, 256, 0, stream>>>(cs, sn);

  // ---- teacher projections (split-bf16 MFMA)
  gemm_mfma<128, 128, 2, 2><<<dim3(M / 128, (NH * HD) / 128), 256, 0, stream>>>(hs, wq, qb, M, NH * HD, H);
  gemm_mfma<64, 64, 2, 2><<<dim3(M / 64, (NKV * HD) / 64), 256, 0, stream>>>(hs, wk, kb, M, NKV * HD, H);
  gemm_mfma<64, 64, 2, 2><<<dim3(M / 64, (NKV * HD) / 64), 256, 0, stream>>>(hs, wv, vb, M, NKV * HD, H);
  rope_apply<<<(M * NH * 32) / 256, 256, 0, stream>>>(qb, cs, sn, NH);
  rope_apply<<<(M * NKV * 32) / 256, 256, 0, stream>>>(kb, cs, sn, NKV);
  flash_attn<<<dim3(S / 64, NH, B), 256, 0, stream>>>(qb, kb, vb, qb);  // in-place over Q
  gemm_mfma<128, 128, 2, 2><<<dim3(M / 128, (NH * HD) / 128), 256, 0, stream>>>(qb, wo, out, M, NH * HD, H);

  // ---- student projections (reuse teacher buffers; stream-serial)
  gemm_mfma<128, 128, 2, 2><<<dim3(M / 128, (NH * HD) / 128), 256, 0, stream>>>(hs, wqs, qb, M, NH * HD, H);
  gemm_mfma<64, 64, 2, 2><<<dim3(M / 64, (NKV * HD) / 64), 256, 0, stream>>>(hs, wks, kb, M, NKV * HD, H);
  gemm_mfma<64, 64, 2, 2><<<dim3(M / 64, (NKV * HD) / 64), 256, 0, stream>>>(hs, wvs, vb, M, NKV * HD, H);

  gate_cumsum<<<dim3(NCHUNK, NKV, B), 64, 0, stream>>>(kb, ac, at);
  softmax64<<<(M * NH) / 4, 256, 0, stream>>>(qb, M * NH);
  softmax64<<<(M * NKV) / 4, 256, 0, stream>>>(kb, M * NKV);

  gla_chunk_T<<<dim3(NCHUNK, NKV, B), 256, 0, stream>>>(kb, vb, ac, at, Tb);
  gla_scan_state<<<dim3(NKV, B), 256, 0, stream>>>(at, Tb);
  gla_output<<<dim3(NCHUNK, NH, B), 256, 0, stream>>>(qb, kb, vb, ac, Tb, qb);  // in-place over Q

  // student output projection
  gemm_mfma<128, 128, 2, 2><<<dim3(M / 128, (NH * HD) / 128), 256, 0, stream>>>(qb, wos, out + (size_t)M * (NH * HD), M, NH * HD, H);
}

// Round 6
// 1473.692 us; speedup vs baseline: 2.3190x; 1.3266x over previous
//
#include <hip/hip_runtime.h>
#include <math.h>

namespace {

constexpr int B = 2, S = 2048, NH = 32, NKV = 8, HD = 64, NG = 4;
constexpr int M = B * S;                      // 4096 rows
constexpr int H = 2048;                       // hidden (= K dim of projections)
constexpr int CHUNK = 64, NCHUNK = S / CHUNK; // 32 chunks
constexpr float GATE_NORM = 16.0f;

typedef __attribute__((ext_vector_type(8))) short short8;   // 8 bf16 (4 VGPRs)
typedef __attribute__((ext_vector_type(4))) float f32x4;    // MFMA accum

// ---- workspace layout (floats), 17,072,128 floats = 68.3 MB (proven to fit).
constexpr size_t OFS_COS = 0;
constexpr size_t OFS_SIN = OFS_COS + (size_t)S * HD;
constexpr size_t OFS_Q   = OFS_SIN + (size_t)S * HD;                    // q; overwritten by attn/gla out
constexpr size_t OFS_K   = OFS_Q   + (size_t)M * (NH * HD);
constexpr size_t OFS_V   = OFS_K   + (size_t)M * (NKV * HD);
constexpr size_t OFS_AC  = OFS_V   + (size_t)M * (NKV * HD);
constexpr size_t OFS_AT  = OFS_AC  + (size_t)B * NKV * S * HD;
constexpr size_t OFS_T   = OFS_AT  + (size_t)B * NKV * NCHUNK * HD;

__device__ __forceinline__ ushort bf16_rne(float x) {
  uint u = __float_as_uint(x);
  return (ushort)((u + 0x7FFFu + ((u >> 16) & 1u)) >> 16);
}

// ---------------------------------------------------------------- RoPE tables
__global__ void rope_table(float* __restrict__ cs, float* __restrict__ sn) {
  int id = blockIdx.x * blockDim.x + threadIdx.x;  // S * 32
  if (id >= S * (HD / 2)) return;
  int s = id >> 5, i = id & 31;
  double inv = exp(-(double)(2 * i) / 64.0 * log(500000.0));
  float f = (float)s * (float)inv;
  float c = cosf(f), si = sinf(f);
  cs[s * HD + i] = c;  cs[s * HD + i + 32] = c;
  sn[s * HD + i] = si; sn[s * HD + i + 32] = si;
}

// ----------------------------------------------- split-bf16 MFMA GEMM, C=A*W^T
// (unchanged from the verified-passing round-5 kernel)
template <int BM, int BN, int WR, int WC>
__global__ __launch_bounds__(256) void gemm_mfma(
    const float* __restrict__ A, const float* __restrict__ W,
    float* __restrict__ C, int Mm, int Nn, int Kk) {
  constexpr int BK = 32;
  constexpr int MF = BM / 16, NF = BN / 16;
  constexpr int MFR = MF / WR, NFR = NF / WC;
  constexpr int NA = MF * 64, NB = NF * 64;
  constexpr int CA = NA / 256, CB = NB / 256;
  static_assert(CA >= 1 && CB >= 1 && MF == WR * MFR && NF == WC * NFR, "cfg");
  __shared__ short Ah[NA * 8], Al[NA * 8], Bh[NB * 8], Bl[NB * 8];

  const int t = threadIdx.x;
  const int l = t & 63, w = t >> 6;
  const int wr = w / WC, wc = w % WC;
  const int bm = blockIdx.x * BM, bn = blockIdx.y * BN;

  const float* ga[CA];
  const float* gb[CB];
#pragma unroll
  for (int i = 0; i < CA; ++i) {
    int f = t + i * 256, lf = f & 63;
    int row = (f >> 6) * 16 + (lf & 15), ks = (lf >> 4) * 8;
    ga[i] = A + (size_t)(bm + row) * Kk + ks;
  }
#pragma unroll
  for (int i = 0; i < CB; ++i) {
    int f = t + i * 256, lf = f & 63;
    int col = (f >> 6) * 16 + (lf & 15), ks = (lf >> 4) * 8;
    gb[i] = W + (size_t)(bn + col) * Kk + ks;
  }

  float4 ra[CA * 2], rb[CB * 2];
  auto gload = [&](int k0) {
#pragma unroll
    for (int i = 0; i < CA; ++i) {
      ra[2 * i]     = *(const float4*)(ga[i] + k0);
      ra[2 * i + 1] = *(const float4*)(ga[i] + k0 + 4);
    }
#pragma unroll
    for (int i = 0; i < CB; ++i) {
      rb[2 * i]     = *(const float4*)(gb[i] + k0);
      rb[2 * i + 1] = *(const float4*)(gb[i] + k0 + 4);
    }
  };

  auto split8 = [](float4 x, float4 y, uint* oh, uint* ol) {
    float v0[4] = {x.x, x.y, x.z, x.w};
    float v1[4] = {y.x, y.y, y.z, y.w};
    float v[8];
#pragma unroll
    for (int p = 0; p < 4; ++p) { v[p] = v0[p]; v[p + 4] = v1[p]; }
#pragma unroll
    for (int p = 0; p < 4; ++p) {
      uint u0 = __float_as_uint(v[2 * p]), u1 = __float_as_uint(v[2 * p + 1]);
      float h0 = __uint_as_float(u0 & 0xFFFF0000u);
      float h1 = __uint_as_float(u1 & 0xFFFF0000u);
      uint l0 = __float_as_uint(v[2 * p] - h0), l1 = __float_as_uint(v[2 * p + 1] - h1);
      oh[p] = (u0 >> 16) | (u1 & 0xFFFF0000u);
      ol[p] = (l0 >> 16) | (l1 & 0xFFFF0000u);
    }
  };

  auto cvt_store = [&]() {
#pragma unroll
    for (int i = 0; i < CA; ++i) {
      int f = t + i * 256;
      uint oh[4], ol[4];
      split8(ra[2 * i], ra[2 * i + 1], oh, ol);
      *(int4*)&Ah[f * 8] = make_int4(oh[0], oh[1], oh[2], oh[3]);
      *(int4*)&Al[f * 8] = make_int4(ol[0], ol[1], ol[2], ol[3]);
    }
#pragma unroll
    for (int i = 0; i < CB; ++i) {
      int f = t + i * 256;
      uint oh[4], ol[4];
      split8(rb[2 * i], rb[2 * i + 1], oh, ol);
      *(int4*)&Bh[f * 8] = make_int4(oh[0], oh[1], oh[2], oh[3]);
      *(int4*)&Bl[f * 8] = make_int4(ol[0], ol[1], ol[2], ol[3]);
    }
  };

  f32x4 acc[MFR][NFR] = {};
  gload(0);
  for (int k0 = 0;;) {
    __syncthreads();
    cvt_store();
    __syncthreads();
    k0 += BK;
    bool more = k0 < Kk;
    if (more) gload(k0);

    short8 ah[MFR], al[MFR];
#pragma unroll
    for (int m = 0; m < MFR; ++m) {
      ah[m] = *(const short8*)&Ah[((wr * MFR + m) * 64 + l) * 8];
      al[m] = *(const short8*)&Al[((wr * MFR + m) * 64 + l) * 8];
    }
#pragma unroll
    for (int n = 0; n < NFR; ++n) {
      short8 bh = *(const short8*)&Bh[((wc * NFR + n) * 64 + l) * 8];
      short8 bl = *(const short8*)&Bl[((wc * NFR + n) * 64 + l) * 8];
#pragma unroll
      for (int m = 0; m < MFR; ++m) {
        acc[m][n] = __builtin_amdgcn_mfma_f32_16x16x32_bf16(ah[m], bh, acc[m][n], 0, 0, 0);
        acc[m][n] = __builtin_amdgcn_mfma_f32_16x16x32_bf16(ah[m], bl, acc[m][n], 0, 0, 0);
        acc[m][n] = __builtin_amdgcn_mfma_f32_16x16x32_bf16(al[m], bh, acc[m][n], 0, 0, 0);
      }
    }
    if (!more) break;
  }

#pragma unroll
  for (int m = 0; m < MFR; ++m)
#pragma unroll
    for (int n = 0; n < NFR; ++n) {
      int col = bn + (wc * NFR + n) * 16 + (l & 15);
      int row0 = bm + (wr * MFR + m) * 16 + (l >> 4) * 4;
#pragma unroll
      for (int i = 0; i < 4; ++i)
        C[(size_t)(row0 + i) * Nn + col] = acc[m][n][i];
    }
}

// ------------------------------------------------------------- RoPE in-place
__global__ void rope_apply(float* __restrict__ X, const float* __restrict__ cs,
                           const float* __restrict__ sn, int nh) {
  int id = blockIdx.x * blockDim.x + threadIdx.x;  // M * nh * 32
  int i = id & 31;
  int hm = id >> 5;
  int h = hm % nh;
  int m = hm / nh;
  int s = m & (S - 1);
  float* p = X + (size_t)m * (nh * HD) + h * HD;
  float x1 = p[i], x2 = p[i + 32];
  float c = cs[s * HD + i], si = sn[s * HD + i];
  p[i]      = x1 * c - x2 * si;
  p[i + 32] = x2 * c + x1 * si;
}

// -------------------------------------------- teacher flash attention (MFMA)
// grid (S/64, NH, B), 256 threads = 4 waves, each wave owns 16 q-rows.
// QK^T: split-bf16 Q (regs) x split-bf16 K (LDS) -> 3 MFMAs per frag pair.
// PV:   bf16 P (LDS bounce) x bf16 V^T (LDS) -> 1 MFMA per frag pair.
// Oa may alias Q (Q slice read once into regs at start; written at end).
__global__ __launch_bounds__(256) void flash_attn_mfma(
    const float* __restrict__ Q, const float* __restrict__ K,
    const float* __restrict__ V, float* __restrict__ Oa) {
  constexpr int LD = 72;  // row stride: 144B -> b128 16B-aligned, 4-bank row skew
  __shared__ short Kh[64 * LD];   // K hi  [key][d]
  __shared__ short Kl[64 * LD];   // K lo  [key][d]
  __shared__ short Vt[64 * LD];   // V^T   [v][u]
  __shared__ short Pl[64 * LD];   // P     [4 waves][16 rows][64 keys]
  const int qt = (int)gridDim.x - 1 - (int)blockIdx.x;
  const int h = blockIdx.y, b = blockIdx.z;
  const int kvh = h / NG;
  const int t = threadIdx.x;
  const int l = t & 63, w = t >> 6;
  const int l15 = l & 15, lg = l >> 4;

  // ---- Q A-fragments (hi/lo split), loaded once; row = l15, k = lg*8+e+32ks
  short8 qh[2], ql[2];
#pragma unroll
  for (int ks = 0; ks < 2; ++ks) {
    const float* qp = Q + (size_t)(b * S + qt * 64 + w * 16 + l15) * (NH * HD)
                        + h * HD + lg * 8 + ks * 32;
    float4 x0 = *(const float4*)qp;
    float4 x1 = *(const float4*)(qp + 4);
    float f[8] = {x0.x, x0.y, x0.z, x0.w, x1.x, x1.y, x1.z, x1.w};
#pragma unroll
    for (int e = 0; e < 8; ++e) {
      uint u = __float_as_uint(f[e]);
      float hf = __uint_as_float(u & 0xFFFF0000u);
      qh[ks][e] = (short)(u >> 16);
      ql[ks][e] = (short)bf16_rne(f[e] - hf);
    }
  }

  f32x4 oa[4] = {};         // O accum: frag n covers v = l15+16n; reg i -> row lg*4+i
  float mrun[4], lrun[4];
#pragma unroll
  for (int i = 0; i < 4; ++i) { mrun[i] = -INFINITY; lrun[i] = 0.f; }

  for (int jt = 0; jt <= qt; ++jt) {
    __syncthreads();  // prior tile's Kh/Kl/Vt reads complete
    // ---- stage K (split hi/lo) and V^T, cooperative across 256 threads
#pragma unroll
    for (int r = 0; r < 4; ++r) {
      int idx = t + 256 * r;
      int row = idx >> 4, cq = idx & 15;        // row = key/u ; cq = float4 col
      const float* kp = K + (size_t)(b * S + jt * 64 + row) * (NKV * HD) + kvh * HD + cq * 4;
      const float* vp = V + (size_t)(b * S + jt * 64 + row) * (NKV * HD) + kvh * HD + cq * 4;
      float4 kx = *(const float4*)kp;
      float4 vx = *(const float4*)vp;
      float kf[4] = {kx.x, kx.y, kx.z, kx.w};
      float vf[4] = {vx.x, vx.y, vx.z, vx.w};
      uint khp[4], klp[4];
#pragma unroll
      for (int j = 0; j < 4; ++j) {
        uint u = __float_as_uint(kf[j]);
        float hf = __uint_as_float(u & 0xFFFF0000u);
        khp[j] = u >> 16;
        klp[j] = bf16_rne(kf[j] - hf);
        Vt[(cq * 4 + j) * LD + row] = (short)bf16_rne(vf[j]);
      }
      *(int2*)&Kh[row * LD + cq * 4] =
          make_int2((int)(khp[0] | (khp[1] << 16)), (int)(khp[2] | (khp[3] << 16)));
      *(int2*)&Kl[row * LD + cq * 4] =
          make_int2((int)(klp[0] | (klp[1] << 16)), (int)(klp[2] | (klp[3] << 16)));
    }
    __syncthreads();

    // ---- QK^T: S[16 rows][64 keys] per wave (split-3)
    f32x4 sc[4] = {};
#pragma unroll
    for (int n = 0; n < 4; ++n) {
#pragma unroll
      for (int ks = 0; ks < 2; ++ks) {
        int off = (l15 + 16 * n) * LD + lg * 8 + ks * 32;
        short8 bh = *(const short8*)&Kh[off];
        short8 bl = *(const short8*)&Kl[off];
        sc[n] = __builtin_amdgcn_mfma_f32_16x16x32_bf16(qh[ks], bh, sc[n], 0, 0, 0);
        sc[n] = __builtin_amdgcn_mfma_f32_16x16x32_bf16(qh[ks], bl, sc[n], 0, 0, 0);
        sc[n] = __builtin_amdgcn_mfma_f32_16x16x32_bf16(ql[ks], bh, sc[n], 0, 0, 0);
      }
    }

    // ---- scale + causal mask + online softmax (row = lg*4+i, 16 lanes/row)
    float pf[4][4];  // [n][i]
#pragma unroll
    for (int i = 0; i < 4; ++i) {
      int rloc = w * 16 + lg * 4 + i;  // row within 64-row q tile
      float s0[4];
#pragma unroll
      for (int n = 0; n < 4; ++n) {
        float v = sc[n][i] * 0.125f;
        if (jt == qt && (l15 + 16 * n) > rloc) v = -INFINITY;
        s0[n] = v;
      }
      float mloc = fmaxf(fmaxf(s0[0], s0[1]), fmaxf(s0[2], s0[3]));
#pragma unroll
      for (int mk = 1; mk <= 8; mk <<= 1) mloc = fmaxf(mloc, __shfl_xor(mloc, mk));
      float mnew = fmaxf(mrun[i], mloc);
      float sf = expf(mrun[i] - mnew);
      mrun[i] = mnew;
      float rs = 0.f;
#pragma unroll
      for (int n = 0; n < 4; ++n) {
        float e = expf(s0[n] - mnew);
        pf[n][i] = e;
        rs += e;
      }
#pragma unroll
      for (int mk = 1; mk <= 8; mk <<= 1) rs += __shfl_xor(rs, mk);
      lrun[i] = lrun[i] * sf + rs;
#pragma unroll
      for (int n = 0; n < 4; ++n) oa[n][i] *= sf;
    }

    // ---- P -> bf16 via per-wave LDS slice (write 2-way-free by construction)
#pragma unroll
    for (int n = 0; n < 4; ++n)
#pragma unroll
      for (int i = 0; i < 4; ++i)
        Pl[(w * 16 + lg * 4 + i) * LD + l15 + 16 * n] = (short)bf16_rne(pf[n][i]);
    // same-wave write->read dependency: compiler inserts lgkmcnt wait

    // ---- PV: O += P x V
#pragma unroll
    for (int ks = 0; ks < 2; ++ks) {
      short8 pa = *(const short8*)&Pl[(w * 16 + l15) * LD + lg * 8 + ks * 32];
#pragma unroll
      for (int n = 0; n < 4; ++n) {
        short8 vbf = *(const short8*)&Vt[(l15 + 16 * n) * LD + lg * 8 + ks * 32];
        oa[n] = __builtin_amdgcn_mfma_f32_16x16x32_bf16(pa, vbf, oa[n], 0, 0, 0);
      }
    }
  }

  // ---- epilogue: normalize and write (may alias Q)
#pragma unroll
  for (int i = 0; i < 4; ++i) {
    float inv = 1.f / lrun[i];
    float* op = Oa + (size_t)(b * S + qt * 64 + w * 16 + lg * 4 + i) * (NH * HD)
                   + h * HD + l15;
#pragma unroll
    for (int n = 0; n < 4; ++n) op[16 * n] = oa[n][i] * inv;
  }
}

// ------------------------------------------------- student: row softmax of 64
__global__ void softmax64(float* __restrict__ X, int nrows) {
  int row = blockIdx.x * 4 + (threadIdx.x >> 6);
  int lane = threadIdx.x & 63;
  if (row >= nrows) return;
  float* p = X + (size_t)row * 64;
  float x = p[lane];
  float mx = x;
#pragma unroll
  for (int mk = 32; mk >= 1; mk >>= 1) mx = fmaxf(mx, __shfl_xor(mx, mk));
  float e = expf(x - mx);
  float sm = e;
#pragma unroll
  for (int mk = 32; mk >= 1; mk >>= 1) sm += __shfl_xor(sm, mk);
  p[lane] = e / sm;
}

// ----------------------------------------- student: gate cumsum within chunks
__global__ void gate_cumsum(const float* __restrict__ Kraw, float* __restrict__ Ac,
                            float* __restrict__ At) {
  int c = blockIdx.x, kv = blockIdx.y, b = blockIdx.z, d = threadIdx.x;
  float a = 0.f;
  for (int tt = 0; tt < CHUNK; ++tt) {
    int srow = c * CHUNK + tt;
    float x = Kraw[(size_t)(b * S + srow) * (NKV * HD) + kv * HD + d];
    float g = (x >= 0.f ? -log1pf(expf(-x)) : x - log1pf(expf(x))) / GATE_NORM;
    a += g;
    Ac[((size_t)(b * NKV + kv) * S + srow) * HD + d] = a;
  }
  At[((size_t)(b * NKV + kv) * NCHUNK + c) * HD + d] = a;
}

// -------------------------------- student phase 1: per-chunk outer-product T_c
__global__ __launch_bounds__(256) void gla_chunk_T(
    const float* __restrict__ Ks, const float* __restrict__ Vs,
    const float* __restrict__ Ac, const float* __restrict__ At,
    float* __restrict__ T) {
  __shared__ float kh[CHUNK][HD + 4];
  __shared__ float vh[CHUNK][HD + 4];
  int c = blockIdx.x, kv = blockIdx.y, b = blockIdx.z;
  int t = threadIdx.x, tx = t & 15, ty = t >> 4;
  int lr = t >> 2, lc0 = (t & 3) << 4;
  {
    int srow = c * CHUNK + lr;
    const float* kp = Ks + (size_t)(b * S + srow) * (NKV * HD) + kv * HD + lc0;
    const float* ap = Ac + ((size_t)(b * NKV + kv) * S + srow) * HD + lc0;
    const float* Ap = At + ((size_t)(b * NKV + kv) * NCHUNK + c) * HD + lc0;
    const float* vp = Vs + (size_t)(b * S + srow) * (NKV * HD) + kv * HD + lc0;
#pragma unroll
    for (int q4 = 0; q4 < 4; ++q4) {
      float4 kq = *(const float4*)(kp + q4 * 4);
      float4 aq = *(const float4*)(ap + q4 * 4);
      float4 Aq = *(const float4*)(Ap + q4 * 4);
      float4 vq = *(const float4*)(vp + q4 * 4);
      kh[lr][lc0 + q4 * 4 + 0] = kq.x * expf(Aq.x - aq.x);
      kh[lr][lc0 + q4 * 4 + 1] = kq.y * expf(Aq.y - aq.y);
      kh[lr][lc0 + q4 * 4 + 2] = kq.z * expf(Aq.z - aq.z);
      kh[lr][lc0 + q4 * 4 + 3] = kq.w * expf(Aq.w - aq.w);
      *(float4*)&vh[lr][lc0 + q4 * 4] = vq;
    }
  }
  __syncthreads();
  float acc[4][4];
#pragma unroll
  for (int i = 0; i < 4; ++i)
#pragma unroll
    for (int j = 0; j < 4; ++j) acc[i][j] = 0.f;
#pragma unroll 4
  for (int u = 0; u < CHUNK; ++u) {
    float4 kk = *(const float4*)&kh[u][ty * 4];
    float4 vv = *(const float4*)&vh[u][tx * 4];
    float ka[4] = {kk.x, kk.y, kk.z, kk.w};
    float vb[4] = {vv.x, vv.y, vv.z, vv.w};
#pragma unroll
    for (int i = 0; i < 4; ++i)
#pragma unroll
      for (int j = 0; j < 4; ++j) acc[i][j] = fmaf(ka[i], vb[j], acc[i][j]);
  }
  float* Tp = T + ((size_t)(b * NKV + kv) * NCHUNK + c) * (HD * HD);
#pragma unroll
  for (int i = 0; i < 4; ++i)
    *(float4*)&Tp[(ty * 4 + i) * HD + tx * 4] =
        make_float4(acc[i][0], acc[i][1], acc[i][2], acc[i][3]);
}

// ------------------- student phase 2: chunk scan, T_c slots become S_init(c)
__global__ void gla_scan_state(const float* __restrict__ At, float* __restrict__ T) {
  int kv = blockIdx.x, b = blockIdx.y;
  int t = threadIdx.x;
  int k = t >> 2, v0 = (t & 3) << 4;
  float st[16];
#pragma unroll
  for (int i = 0; i < 16; ++i) st[i] = 0.f;
  size_t base = (size_t)(b * NKV + kv) * NCHUNK;
  for (int c = 0; c < NCHUNK; ++c) {
    float* Tp = T + (base + c) * (HD * HD) + k * HD + v0;
    float dec = expf(At[(base + c) * HD + k]);
    float tmp[16];
#pragma unroll
    for (int q = 0; q < 4; ++q) {
      float4 x = *(const float4*)(Tp + q * 4);
      tmp[q * 4 + 0] = x.x; tmp[q * 4 + 1] = x.y; tmp[q * 4 + 2] = x.z; tmp[q * 4 + 3] = x.w;
    }
#pragma unroll
    for (int q = 0; q < 4; ++q)
      *(float4*)(Tp + q * 4) =
          make_float4(st[q * 4 + 0], st[q * 4 + 1], st[q * 4 + 2], st[q * 4 + 3]);
#pragma unroll
    for (int i = 0; i < 16; ++i) st[i] = st[i] * dec + tmp[i];
  }
}

// ------------------------- student phase 3: per-chunk outputs (inter + intra)
__global__ __launch_bounds__(256) void gla_output(
    const float* __restrict__ Qs, const float* __restrict__ Ks,
    const float* __restrict__ Vs, const float* __restrict__ Ac,
    const float* __restrict__ Sini, float* __restrict__ Go) {
  __shared__ float qsh[HD][CHUNK + 4];
  __shared__ float ksh[HD][CHUNK + 4];
  __shared__ float psh[CHUNK][CHUNK + 4];
  int c = blockIdx.x, h = blockIdx.y, b = blockIdx.z;
  int kv = h / NG;
  int t = threadIdx.x, tx = t & 15, ty = t >> 4;
  int lr = t >> 2, lc0 = (t & 3) << 4;
  {
    int srow = c * CHUNK + lr;
    const float* qp = Qs + (size_t)(b * S + srow) * (NH * HD) + h * HD + lc0;
    const float* ap = Ac + ((size_t)(b * NKV + kv) * S + srow) * HD + lc0;
    const float* kp = Ks + (size_t)(b * S + srow) * (NKV * HD) + kv * HD + lc0;
#pragma unroll
    for (int q4 = 0; q4 < 4; ++q4) {
      float4 qv = *(const float4*)(qp + q4 * 4);
      float4 av = *(const float4*)(ap + q4 * 4);
      float4 kq = *(const float4*)(kp + q4 * 4);
      float e0 = expf(av.x), e1 = expf(av.y), e2 = expf(av.z), e3 = expf(av.w);
      qsh[lc0 + q4 * 4 + 0][lr] = qv.x * e0;
      qsh[lc0 + q4 * 4 + 1][lr] = qv.y * e1;
      qsh[lc0 + q4 * 4 + 2][lr] = qv.z * e2;
      qsh[lc0 + q4 * 4 + 3][lr] = qv.w * e3;
      ksh[lc0 + q4 * 4 + 0][lr] = kq.x / e0;
      ksh[lc0 + q4 * 4 + 1][lr] = kq.y / e1;
      ksh[lc0 + q4 * 4 + 2][lr] = kq.z / e2;
      ksh[lc0 + q4 * 4 + 3][lr] = kq.w / e3;
    }
  }
  __syncthreads();
  float p[4][4];
#pragma unroll
  for (int i = 0; i < 4; ++i)
#pragma unroll
    for (int j = 0; j < 4; ++j) p[i][j] = 0.f;
#pragma unroll 4
  for (int d = 0; d < HD; ++d) {
    float4 qv = *(const float4*)&qsh[d][ty * 4];
    float4 kq = *(const float4*)&ksh[d][tx * 4];
    float qa[4] = {qv.x, qv.y, qv.z, qv.w};
    float kb[4] = {kq.x, kq.y, kq.z, kq.w};
#pragma unroll
    for (int i = 0; i < 4; ++i)
#pragma unroll
      for (int j = 0; j < 4; ++j) p[i][j] = fmaf(qa[i], kb[j], p[i][j]);
  }
#pragma unroll
  for (int i = 0; i < 4; ++i)
#pragma unroll
    for (int j = 0; j < 4; ++j) {
      if (tx * 4 + j > ty * 4 + i) p[i][j] = 0.f;
      psh[tx * 4 + j][ty * 4 + i] = p[i][j];
    }
  __syncthreads();
  {
    const float* Sp = Sini + ((size_t)(b * NKV + kv) * NCHUNK + c) * (HD * HD) + lr * HD + lc0;
#pragma unroll
    for (int q4 = 0; q4 < 4; ++q4)
      *(float4*)&ksh[lr][lc0 + q4 * 4] = *(const float4*)(Sp + q4 * 4);
  }
  __syncthreads();
  float o[4][4];
#pragma unroll
  for (int i = 0; i < 4; ++i)
#pragma unroll
    for (int j = 0; j < 4; ++j) o[i][j] = 0.f;
#pragma unroll 4
  for (int d = 0; d < HD; ++d) {
    float4 qv = *(const float4*)&qsh[d][ty * 4];
    float4 sv = *(const float4*)&ksh[d][tx * 4];
    float qa[4] = {qv.x, qv.y, qv.z, qv.w};
    float sb[4] = {sv.x, sv.y, sv.z, sv.w};
#pragma unroll
    for (int i = 0; i < 4; ++i)
#pragma unroll
      for (int j = 0; j < 4; ++j) o[i][j] = fmaf(qa[i], sb[j], o[i][j]);
  }
  __syncthreads();
  {
    const float* vp = Vs + (size_t)(b * S + c * CHUNK + lr) * (NKV * HD) + kv * HD + lc0;
#pragma unroll
    for (int q4 = 0; q4 < 4; ++q4)
      *(float4*)&qsh[lr][lc0 + q4 * 4] = *(const float4*)(vp + q4 * 4);
  }
  __syncthreads();
#pragma unroll 4
  for (int u = 0; u < CHUNK; ++u) {
    float4 pv = *(const float4*)&psh[u][ty * 4];
    float4 vv = *(const float4*)&qsh[u][tx * 4];
    float pa[4] = {pv.x, pv.y, pv.z, pv.w};
    float vb[4] = {vv.x, vv.y, vv.z, vv.w};
#pragma unroll
    for (int i = 0; i < 4; ++i)
#pragma unroll
      for (int j = 0; j < 4; ++j) o[i][j] = fmaf(pa[i], vb[j], o[i][j]);
  }
#pragma unroll
  for (int i = 0; i < 4; ++i) {
    float* gp = Go + (size_t)(b * S + c * CHUNK + ty * 4 + i) * (NH * HD) + h * HD + tx * 4;
    *(float4*)gp = make_float4(o[i][0], o[i][1], o[i][2], o[i][3]);
  }
}

}  // namespace

extern "C" void kernel_launch(void* const* d_in, const int* in_sizes, int n_in,
                              void* d_out, int out_size, void* d_ws, size_t ws_size,
                              hipStream_t stream) {
  (void)in_sizes; (void)n_in; (void)out_size; (void)ws_size;
  const float* hs  = (const float*)d_in[0];
  const float* wq  = (const float*)d_in[1];
  const float* wk  = (const float*)d_in[2];
  const float* wv  = (const float*)d_in[3];
  const float* wo  = (const float*)d_in[4];
  const float* wqs = (const float*)d_in[5];
  const float* wks = (const float*)d_in[6];
  const float* wvs = (const float*)d_in[7];
  const float* wos = (const float*)d_in[8];
  float* out = (float*)d_out;
  float* ws  = (float*)d_ws;

  float* cs = ws + OFS_COS;
  float* sn = ws + OFS_SIN;
  float* qb = ws + OFS_Q;
  float* kb = ws + OFS_K;
  float* vb = ws + OFS_V;
  float* ac = ws + OFS_AC;
  float* at = ws + OFS_AT;
  float* Tb = ws + OFS_T;

  rope_table<<<(S * (HD / 2)) / 256, 256, 0, stream>>>(cs, sn);

  // ---- teacher projections (split-bf16 MFMA)
  gemm_mfma<128, 128, 2, 2><<<dim3(M / 128, (NH * HD) / 128), 256, 0, stream>>>(hs, wq, qb, M, NH * HD, H);
  gemm_mfma<64, 64, 2, 2><<<dim3(M / 64, (NKV * HD) / 64), 256, 0, stream>>>(hs, wk, kb, M, NKV * HD, H);
  gemm_mfma<64, 64, 2, 2><<<dim3(M / 64, (NKV * HD) / 64), 256, 0, stream>>>(hs, wv, vb, M, NKV * HD, H);
  rope_apply<<<(M * NH * 32) / 256, 256, 0, stream>>>(qb, cs, sn, NH);
  rope_apply<<<(M * NKV * 32) / 256, 256, 0, stream>>>(kb, cs, sn, NKV);
  flash_attn_mfma<<<dim3(S / 64, NH, B), 256, 0, stream>>>(qb, kb, vb, qb);  // in-place over Q
  gemm_mfma<128, 128, 2, 2><<<dim3(M / 128, (NH * HD) / 128), 256, 0, stream>>>(qb, wo, out, M, NH * HD, H);

  // ---- student projections (reuse teacher buffers; stream-serial)
  gemm_mfma<128, 128, 2, 2><<<dim3(M / 128, (NH * HD) / 128), 256, 0, stream>>>(hs, wqs, qb, M, NH * HD, H);
  gemm_mfma<64, 64, 2, 2><<<dim3(M / 64, (NKV * HD) / 64), 256, 0, stream>>>(hs, wks, kb, M, NKV * HD, H);
  gemm_mfma<64, 64, 2, 2><<<dim3(M / 64, (NKV * HD) / 64), 256, 0, stream>>>(hs, wvs, vb, M, NKV * HD, H);

  gate_cumsum<<<dim3(NCHUNK, NKV, B), 64, 0, stream>>>(kb, ac, at);
  softmax64<<<(M * NH) / 4, 256, 0, stream>>>(qb, M * NH);
  softmax64<<<(M * NKV) / 4, 256, 0, stream>>>(kb, M * NKV);

  gla_chunk_T<<<dim3(NCHUNK, NKV, B), 256, 0, stream>>>(kb, vb, ac, at, Tb);
  gla_scan_state<<<dim3(NKV, B), 256, 0, stream>>>(at, Tb);
  gla_output<<<dim3(NCHUNK, NH, B), 256, 0, stream>>>(qb, kb, vb, ac, Tb, qb);  // in-place over Q

  // student output projection
  gemm_mfma<128, 128, 2, 2><<<dim3(M / 128, (NH * HD) / 128), 256, 0, stream>>>(qb, wos, out + (size_t)M * (NH * HD), M, NH * HD, H);
}